// Round 6
// baseline (317.613 us; speedup 1.0000x reference)
//
#include <hip/hip_runtime.h>
#include <hip/hip_bf16.h>

// Problem constants (fixed by reference file)
#define EMBED    256
#define HEADS    8
#define LEVELS   4
#define POINTS   4
#define HEAD_DIM 32
#define BS       8
#define NQ       900
#define NV       13294          // 100*100 + 50*50 + 25*25 + 13*13
#define MV       (BS*NV)        // 106352 = 6647*16
#define MQ       (BS*NQ)        // 7200   = 450*16
#define NQOUT    384            // 256 offset cols + 128 attn cols

typedef float  f32x4  __attribute__((ext_vector_type(4)));
typedef __bf16 bf16x8 __attribute__((ext_vector_type(8)));
typedef unsigned short ushort8  __attribute__((ext_vector_type(8)));
typedef unsigned short ushort4v __attribute__((ext_vector_type(4)));

__device__ __forceinline__ unsigned short f2bf(float f) {
    unsigned u = __builtin_bit_cast(unsigned, f);
    u += 0x7FFFu + ((u >> 16) & 1u);          // RNE
    return (unsigned short)(u >> 16);
}
__device__ __forceinline__ float bf2f(unsigned short h) {
    unsigned u = ((unsigned)h) << 16;
    return __builtin_bit_cast(float, u);
}

// ---------------------------------------------------------------------------
// Prep: transpose + cast weights to bf16 (B^T layout: [n][k], k contiguous)
// ---------------------------------------------------------------------------
__global__ __launch_bounds__(256) void prep_kernel(
    const float* __restrict__ Wv,  const float* __restrict__ Woff,
    const float* __restrict__ Wattn, const float* __restrict__ Wout,
    const float* __restrict__ boff, const float* __restrict__ battn,
    unsigned short* __restrict__ WtV, unsigned short* __restrict__ WtQ,
    unsigned short* __restrict__ WtO, float* __restrict__ biasQ)
{
    int n = blockIdx.x;      // 0..383
    int k = threadIdx.x;     // 0..255
    if (n < 256) {
        WtV[n * 256 + k] = f2bf(Wv [k * 256 + n]);
        WtO[n * 256 + k] = f2bf(Wout[k * 256 + n]);
        WtQ[n * 256 + k] = f2bf(Woff[k * 256 + n]);
    } else {
        int j = n - 256;
        WtQ[n * 256 + k] = f2bf(Wattn[k * 128 + j]);
    }
    if (k == 0) biasQ[n] = (n < 256) ? boff[n] : battn[n - 256];
}

// ---------------------------------------------------------------------------
// Register-pipelined streaming GEMM (K=256, N = WPB*64).
// Round-5 showed: clean (no spills, no LDS) but 1.2 TB/s — the strip loop is
// serial per wave (loads -> wait -> compute -> store -> next loads), queue
// empty during compute. Fix: REGISTER DOUBLE-BUFFER, strips processed 2 at a
// time with compile-time buffer parity (runtime-indexed reg arrays spill —
// round-3 lesson). Loads(s+1) are issued before compute(s); since they also
// precede stores(s) in the vmcnt FIFO, neither latency nor store-drain blocks.
//   C[M x N] = A[M x 256](fp32) * Bt[n][k]^T + bias (+ Ident)
// MFMA operands swapped (weights = A-op): lane's 4 acc regs are 4 consecutive
// output columns. wf may be demoted to per-strip L2 reloads by the allocator
// (round-5 behavior) — harmless, weights are L2-hot.
// ---------------------------------------------------------------------------
template <int WPB, bool OUT_BF16, bool ADD_ID>
struct GemmOps {
    static constexpr int N = WPB * 64;

    __device__ static void load_strip(f32x4 (&pa)[16], const float* __restrict__ A,
                                      int s, int lrow, int kq) {
        const float* ab = A + (size_t)(s * 16 + lrow) * 256 + kq * 8;
        #pragma unroll
        for (int c = 0; c < 8; ++c) {
            pa[2 * c]     = *(const f32x4*)(ab + c * 32);
            pa[2 * c + 1] = *(const f32x4*)(ab + c * 32 + 4);
        }
    }

    __device__ static void compute_store(const f32x4 (&pa)[16],
                                         const bf16x8 (&wf)[4][8],
                                         const f32x4 (&bj)[4],
                                         const float* __restrict__ Ident,
                                         void* __restrict__ Cv,
                                         int s, int lrow, int kq, int n0) {
        f32x4 acc[4];
        #pragma unroll
        for (int j = 0; j < 4; ++j) acc[j] = (f32x4)0.f;
        #pragma unroll
        for (int c = 0; c < 8; ++c) {
            ushort8 vb;
            #pragma unroll
            for (int e = 0; e < 4; ++e) {
                vb[e]     = f2bf(pa[2 * c][e]);
                vb[4 + e] = f2bf(pa[2 * c + 1][e]);
            }
            bf16x8 vf = __builtin_bit_cast(bf16x8, vb);
            #pragma unroll
            for (int j = 0; j < 4; ++j)
                acc[j] = __builtin_amdgcn_mfma_f32_16x16x32_bf16(
                    wf[j][c], vf, acc[j], 0, 0, 0);
        }
        const size_t crow = (size_t)(s * 16 + lrow) * N + n0 + kq * 4;
        #pragma unroll
        for (int j = 0; j < 4; ++j) {
            f32x4 r = acc[j] + bj[j];
            if (ADD_ID)
                r += *(const f32x4*)(Ident + crow + j * 16);
            if (OUT_BF16) {
                ushort4v o;
                #pragma unroll
                for (int e = 0; e < 4; ++e) o[e] = f2bf(r[e]);
                *(ushort4v*)((unsigned short*)Cv + crow + j * 16) = o;
            } else {
                *(f32x4*)((float*)Cv + crow + j * 16) = r;
            }
        }
    }
};

template <int WPB, bool OUT_BF16, bool ADD_ID>
__global__ __launch_bounds__(WPB * 64, 1)
void gemm_regw(const float* __restrict__ A,
               const unsigned short* __restrict__ Bt,   // [WPB*64][256] bf16
               const float* __restrict__ bias,          // [WPB*64]
               const float* __restrict__ Ident,         // [M][WPB*64] or null
               void* __restrict__ Cv, int M)
{
    using Ops = GemmOps<WPB, OUT_BF16, ADD_ID>;
    const int tid  = threadIdx.x;
    const int wave = tid >> 6, lane = tid & 63;
    const int lrow = lane & 15, kq = lane >> 4;
    const int n0   = wave * 64;                 // wave's column block

    // weights for this wave's 64 columns (allocator may demote to L2 reloads)
    bf16x8 wf[4][8];
    #pragma unroll
    for (int j = 0; j < 4; ++j)
        #pragma unroll
        for (int c = 0; c < 8; ++c)
            wf[j][c] = *(const bf16x8*)(Bt + (size_t)(n0 + j * 16 + lrow) * 256
                                           + c * 32 + kq * 8);
    f32x4 bj[4];
    #pragma unroll
    for (int j = 0; j < 4; ++j)
        bj[j] = *(const f32x4*)(bias + n0 + j * 16 + kq * 4);

    const int NS    = M / 16;
    const int chunk = (NS + gridDim.x - 1) / gridDim.x;
    const int sbeg  = blockIdx.x * chunk;
    const int send  = min(NS, sbeg + chunk);
    if (sbeg >= send) return;

    f32x4 buf0[16], buf1[16];
    Ops::load_strip(buf0, A, sbeg, lrow, kq);
    for (int s = sbeg; s < send; s += 2) {
        if (s + 1 < send) Ops::load_strip(buf1, A, s + 1, lrow, kq);
        Ops::compute_store(buf0, wf, bj, Ident, Cv, s, lrow, kq, n0);
        if (s + 1 < send) {
            if (s + 2 < send) Ops::load_strip(buf0, A, s + 2, lrow, kq);
            Ops::compute_store(buf1, wf, bj, Ident, Cv, s + 1, lrow, kq, n0);
        }
    }
}

// ---------------------------------------------------------------------------
// Sampling: 16 lanes per (b,q,h) triple; lane s (0..15) owns sample s=l*4+p.
// Branchless gathers: index clamped, validity folded into the weight -> all
// 64 loads issue without exec-mask branches; two accumulator pairs split the
// FMA dependency chain.
// ---------------------------------------------------------------------------
__device__ const int   LVL_W[4]  = {100, 50, 25, 13};
__device__ const int   LVL_H[4]  = {100, 50, 25, 13};
__device__ const int   LVL_S[4]  = {0, 10000, 12500, 13125};

__global__ __launch_bounds__(256) void sample_kernel(
    const unsigned short* __restrict__ V,   // (BS*NV, 256) bf16
    const float* __restrict__ Qout,         // (BS*NQ, 384)
    const float* __restrict__ RP,           // (BS, NQ, 4, 2)
    float* __restrict__ OutS)               // (BS*NQ, 256)
{
    const int gid = blockIdx.x * 16 + (threadIdx.x >> 4);   // triple index
    const int s   = threadIdx.x & 15;                       // lane-in-group
    const int h   = gid & 7;
    const int bq  = gid >> 3;                               // b*NQ + q
    const int b   = bq / NQ;

    const float* qrow = Qout + (size_t)bq * NQOUT;

    const int l = s >> 2;
    const float ox = qrow[h * 32 + 2 * s];
    const float oy = qrow[h * 32 + 2 * s + 1];
    float logit    = qrow[256 + h * 16 + s];
    const float rpx = RP[((size_t)bq * 4 + l) * 2 + 0];
    const float rpy = RP[((size_t)bq * 4 + l) * 2 + 1];
    int W = LVL_W[l], H = LVL_H[l], st = LVL_S[l];
    float x = rpx * (float)W + ox - 0.5f;
    float y = rpy * (float)H + oy - 0.5f;
    float fx = floorf(x), fy = floorf(y);
    float lx = x - fx, ly = y - fy;
    int ix = (int)fx, iy = (int)fy;

    // softmax over the 16 lanes of this group
    float mx = logit;
    #pragma unroll
    for (int o = 8; o; o >>= 1) mx = fmaxf(mx, __shfl_xor(mx, o, 16));
    float e = __expf(logit - mx);
    float sum = e;
    #pragma unroll
    for (int o = 8; o; o >>= 1) sum += __shfl_xor(sum, o, 16);
    const float wgt = e / sum;

    const unsigned short* vb = V + ((size_t)b * NV) * 256 + h * 32 + 2 * s;
    float ax0 = 0.f, ay0 = 0.f, ax1 = 0.f, ay1 = 0.f;

    #pragma unroll
    for (int sp = 0; sp < 16; ++sp) {
        float ws  = __shfl(wgt, sp, 16);
        float lxs = __shfl(lx,  sp, 16);
        float lys = __shfl(ly,  sp, 16);
        int  ixs  = __shfl(ix,  sp, 16);
        int  iys  = __shfl(iy,  sp, 16);
        int  Ws   = __shfl(W,   sp, 16);
        int  Hs   = __shfl(H,   sp, 16);
        int  sts  = __shfl(st,  sp, 16);
        #pragma unroll
        for (int corner = 0; corner < 4; ++corner) {
            int dx = corner & 1, dy = corner >> 1;
            int xi = ixs + dx, yi = iys + dy;
            float valid = (xi >= 0 && xi < Ws && yi >= 0 && yi < Hs) ? 1.f : 0.f;
            int xc = min(max(xi, 0), Ws - 1);
            int yc = min(max(yi, 0), Hs - 1);
            float cw = ws * (dx ? lxs : 1.f - lxs) * (dy ? lys : 1.f - lys) * valid;
            const unsigned short* p = vb + (size_t)(sts + yc * Ws + xc) * 256;
            unsigned pv = *(const unsigned*)p;       // 2 bf16, unconditional
            if (corner & 1) {
                ax1 = fmaf(cw, bf2f((unsigned short)(pv & 0xFFFF)), ax1);
                ay1 = fmaf(cw, bf2f((unsigned short)(pv >> 16)), ay1);
            } else {
                ax0 = fmaf(cw, bf2f((unsigned short)(pv & 0xFFFF)), ax0);
                ay0 = fmaf(cw, bf2f((unsigned short)(pv >> 16)), ay0);
            }
        }
    }
    float2* o = (float2*)(OutS + (size_t)bq * 256 + h * 32);
    o[s] = make_float2(ax0 + ax1, ay0 + ay1);
}

// ---------------------------------------------------------------------------
extern "C" void kernel_launch(void* const* d_in, const int* in_sizes, int n_in,
                              void* d_out, int out_size, void* d_ws, size_t ws_size,
                              hipStream_t stream)
{
    const float* query  = (const float*)d_in[0];
    const float* value  = (const float*)d_in[1];
    const float* rp     = (const float*)d_in[2];
    // d_in[3] spatial_shapes: static, hardcoded
    const float* W_off  = (const float*)d_in[4];
    const float* b_off  = (const float*)d_in[5];
    const float* W_attn = (const float*)d_in[6];
    const float* b_attn = (const float*)d_in[7];
    const float* W_v    = (const float*)d_in[8];
    const float* b_v    = (const float*)d_in[9];
    const float* W_out  = (const float*)d_in[10];
    const float* b_out  = (const float*)d_in[11];

    char* ws = (char*)d_ws;
    size_t off = 0;
    unsigned short* Vbf = (unsigned short*)(ws + off); off += (size_t)MV * 256 * 2;
    float* qout         = (float*)(ws + off);          off += (size_t)MQ * NQOUT * 4;
    float* outs         = (float*)(ws + off);          off += (size_t)MQ * 256 * 4;
    unsigned short* WtV = (unsigned short*)(ws + off); off += 256 * 256 * 2;
    unsigned short* WtQ = (unsigned short*)(ws + off); off += 384 * 256 * 2;
    unsigned short* WtO = (unsigned short*)(ws + off); off += 256 * 256 * 2;
    float* biasQ        = (float*)(ws + off);          off += 384 * 4;

    prep_kernel<<<384, 256, 0, stream>>>(W_v, W_off, W_attn, W_out, b_off, b_attn,
                                         WtV, WtQ, WtO, biasQ);

    // v = value @ W_v + b_v -> bf16.  512 blocks x 4 waves, 13 strips/block.
    gemm_regw<4, true, false><<<512, 256, 0, stream>>>(
        value, WtV, b_v, nullptr, Vbf, MV);

    // [off | attn-logits] = query @ [W_off | W_attn] + bias.  450 blocks, 1 strip.
    gemm_regw<6, false, false><<<450, 384, 0, stream>>>(
        query, WtQ, biasQ, nullptr, qout, MQ);

    sample_kernel<<<(BS * NQ * HEADS) / 16, 256, 0, stream>>>(Vbf, qout, rp, outs);

    // out = out_s @ W_out + b_out + query.  450 blocks, 1 strip.
    gemm_regw<4, false, true><<<450, 256, 0, stream>>>(
        outs, WtO, b_out, query, (float*)d_out, MQ);
}

// Round 7
// 285.285 us; speedup vs baseline: 1.1133x; 1.1133x over previous
//
#include <hip/hip_runtime.h>
#include <hip/hip_bf16.h>

// Problem constants (fixed by reference file)
#define EMBED    256
#define HEADS    8
#define LEVELS   4
#define POINTS   4
#define HEAD_DIM 32
#define BS       8
#define NQ       900
#define NV       13294          // 100*100 + 50*50 + 25*25 + 13*13
#define MV       (BS*NV)        // 106352 = 6647*16
#define MQ       (BS*NQ)        // 7200   = 450*16
#define NQOUT    384            // 256 offset cols + 128 attn cols

typedef float  f32x4  __attribute__((ext_vector_type(4)));
typedef __bf16 bf16x8 __attribute__((ext_vector_type(8)));
typedef unsigned short ushort8  __attribute__((ext_vector_type(8)));
typedef unsigned short ushort4v __attribute__((ext_vector_type(4)));

__device__ __forceinline__ unsigned short f2bf(float f) {
    unsigned u = __builtin_bit_cast(unsigned, f);
    u += 0x7FFFu + ((u >> 16) & 1u);          // RNE
    return (unsigned short)(u >> 16);
}
__device__ __forceinline__ float bf2f(unsigned short h) {
    unsigned u = ((unsigned)h) << 16;
    return __builtin_bit_cast(float, u);
}

// ---------------------------------------------------------------------------
// Prep: transpose + cast weights to bf16 (B^T layout: [n][k], k contiguous)
// ---------------------------------------------------------------------------
__global__ __launch_bounds__(256) void prep_kernel(
    const float* __restrict__ Wv,  const float* __restrict__ Woff,
    const float* __restrict__ Wattn, const float* __restrict__ Wout,
    const float* __restrict__ boff, const float* __restrict__ battn,
    unsigned short* __restrict__ WtV, unsigned short* __restrict__ WtQ,
    unsigned short* __restrict__ WtO, float* __restrict__ biasQ)
{
    int n = blockIdx.x;      // 0..383
    int k = threadIdx.x;     // 0..255
    if (n < 256) {
        WtV[n * 256 + k] = f2bf(Wv [k * 256 + n]);
        WtO[n * 256 + k] = f2bf(Wout[k * 256 + n]);
        WtQ[n * 256 + k] = f2bf(Woff[k * 256 + n]);
    } else {
        int j = n - 256;
        WtQ[n * 256 + k] = f2bf(Wattn[k * 128 + j]);
    }
    if (k == 0) biasQ[n] = (n < 256) ? boff[n] : battn[n - 256];
}

// ---------------------------------------------------------------------------
// LDS-weight streaming GEMM (K=256). Rounds 3-6 lesson: the algorithm wants
// weights(128 regs) + A-dbuf(128) + acc in registers; the allocator refuses
// and either spills (r3/4) or demotes weights to serial per-MFMA L2 reloads
// (r5/6, the 82us killer). Fix: weights live in LDS (ds_read_b128 ~8-12cyc,
// fine-grained lgkmcnt -> no latency chain), A uses a HALF-STRIP (K=128)
// register double-buffer = 2x32 VGPRs. Total ~130 VGPRs -> nothing to demote.
// Block: 256 thr = 4 waves = 2 colsets x 2 strip-parities, 128 cols/block,
// LDS 128x272 ushorts = 69.6 KB -> 2 blocks/CU. One barrier total.
// Steady state: compute(h0,s) covers load(h1,s); compute(h1,s) covers
// load(h0,s+2); stores precede next loads in the vmcnt FIFO.
//   C[M x Ntot] slice = A[M x 256](fp32) @ Bt[n][k]^T + bias (+ Ident)
// MFMA operands swapped (weights = A-op): lane's 4 acc regs = 4 consecutive
// output cols. LDS stride 272 ushorts (136 dw = 8 mod 32): b128 fragment
// reads spread uniformly 8/bank (the b128 minimum).
// ---------------------------------------------------------------------------
template <int WPB, bool OUT_BF16, bool ADD_ID>
__global__ __launch_bounds__(WPB * 128)
void gemm_ldsw(const float* __restrict__ A,
               const unsigned short* __restrict__ Bt,   // [Ntot][256] bf16
               const float* __restrict__ bias,          // [Ntot]
               const float* __restrict__ Ident,         // [M][Ntot] or null
               void* __restrict__ Cv, int M, int Ntot)
{
    constexpr int NC   = WPB * 64;     // cols per block
    constexpr int NTHR = WPB * 128;
    const int n0g = blockIdx.y * NC;
    __shared__ unsigned short Ws[NC * 272];

    const int tid = threadIdx.x;
    #pragma unroll
    for (int i = 0; i < (NC * 256 / 8) / NTHR; ++i) {   // 16 iters
        int flat = i * NTHR + tid;                      // ushort8 index
        int row = flat >> 5, col = (flat & 31) * 8;     // 32 vec8 per row
        *(ushort8*)&Ws[row * 272 + col] =
            *(const ushort8*)(Bt + (size_t)(n0g + row) * 256 + col);
    }
    __syncthreads();                                    // the only barrier

    const int wave = tid >> 6, lane = tid & 63;
    const int colset = wave % WPB, parity = wave / WPB; // parity in {0,1}
    const int lrow = lane & 15, kq = lane >> 4;
    const int n0 = colset * 64;

    f32x4 bj[4];
    #pragma unroll
    for (int j = 0; j < 4; ++j)
        bj[j] = *(const f32x4*)(bias + n0g + n0 + j * 16 + kq * 4);

    const int NS    = M / 16;
    const int chunk = (NS + gridDim.x - 1) / gridDim.x;
    const int send  = min(NS, blockIdx.x * chunk + chunk);
    int s = blockIdx.x * chunk + parity;
    if (s >= send) return;

    auto loadHalf = [&](f32x4 (&b)[8], int ss, int h) {
        const float* ab = A + (size_t)(ss * 16 + lrow) * 256 + h * 128 + kq * 8;
        #pragma unroll
        for (int c = 0; c < 4; ++c) {
            b[2 * c]     = *(const f32x4*)(ab + c * 32);
            b[2 * c + 1] = *(const f32x4*)(ab + c * 32 + 4);
        }
    };
    auto computeHalf = [&](f32x4 (&b)[8], int h, f32x4 (&acc)[4]) {
        #pragma unroll
        for (int c = 0; c < 4; ++c) {
            ushort8 vb;
            #pragma unroll
            for (int e = 0; e < 4; ++e) {
                vb[e]     = f2bf(b[2 * c][e]);
                vb[4 + e] = f2bf(b[2 * c + 1][e]);
            }
            bf16x8 vf = __builtin_bit_cast(bf16x8, vb);
            #pragma unroll
            for (int j = 0; j < 4; ++j) {
                bf16x8 wf = *(const bf16x8*)
                    &Ws[(n0 + j * 16 + lrow) * 272 + h * 128 + c * 32 + kq * 8];
                acc[j] = __builtin_amdgcn_mfma_f32_16x16x32_bf16(wf, vf, acc[j], 0, 0, 0);
            }
        }
    };

    f32x4 b0[8], b1[8];
    loadHalf(b0, s, 0);
    while (true) {
        loadHalf(b1, s, 1);
        f32x4 acc[4];
        #pragma unroll
        for (int j = 0; j < 4; ++j) acc[j] = (f32x4)0.f;
        computeHalf(b0, 0, acc);            // waits only on b0
        const int sn = s + 2;
        const bool more = sn < send;
        if (more) loadHalf(b0, sn, 0);      // in flight during computeHalf(b1)
        computeHalf(b1, 1, acc);

        const size_t crow = (size_t)(s * 16 + lrow) * Ntot + n0g + n0 + kq * 4;
        #pragma unroll
        for (int j = 0; j < 4; ++j) {
            f32x4 r = acc[j] + bj[j];
            if (ADD_ID)
                r += *(const f32x4*)(Ident + crow + j * 16);
            if (OUT_BF16) {
                ushort4v o;
                #pragma unroll
                for (int e = 0; e < 4; ++e) o[e] = f2bf(r[e]);
                *(ushort4v*)((unsigned short*)Cv + crow + j * 16) = o;
            } else {
                *(f32x4*)((float*)Cv + crow + j * 16) = r;
            }
        }
        if (!more) break;
        s = sn;
    }
}

// ---------------------------------------------------------------------------
// Sampling: 16 lanes per (b,q,h) triple; lane s (0..15) owns sample s=l*4+p.
// Branchless gathers: index clamped, validity folded into the weight.
// ---------------------------------------------------------------------------
__device__ const int   LVL_W[4]  = {100, 50, 25, 13};
__device__ const int   LVL_H[4]  = {100, 50, 25, 13};
__device__ const int   LVL_S[4]  = {0, 10000, 12500, 13125};

__global__ __launch_bounds__(256) void sample_kernel(
    const unsigned short* __restrict__ V,   // (BS*NV, 256) bf16
    const float* __restrict__ Qout,         // (BS*NQ, 384)
    const float* __restrict__ RP,           // (BS, NQ, 4, 2)
    float* __restrict__ OutS)               // (BS*NQ, 256)
{
    const int gid = blockIdx.x * 16 + (threadIdx.x >> 4);   // triple index
    const int s   = threadIdx.x & 15;                       // lane-in-group
    const int h   = gid & 7;
    const int bq  = gid >> 3;                               // b*NQ + q
    const int b   = bq / NQ;

    const float* qrow = Qout + (size_t)bq * NQOUT;

    const int l = s >> 2;
    const float ox = qrow[h * 32 + 2 * s];
    const float oy = qrow[h * 32 + 2 * s + 1];
    float logit    = qrow[256 + h * 16 + s];
    const float rpx = RP[((size_t)bq * 4 + l) * 2 + 0];
    const float rpy = RP[((size_t)bq * 4 + l) * 2 + 1];
    int W = LVL_W[l], H = LVL_H[l], st = LVL_S[l];
    float x = rpx * (float)W + ox - 0.5f;
    float y = rpy * (float)H + oy - 0.5f;
    float fx = floorf(x), fy = floorf(y);
    float lx = x - fx, ly = y - fy;
    int ix = (int)fx, iy = (int)fy;

    // softmax over the 16 lanes of this group
    float mx = logit;
    #pragma unroll
    for (int o = 8; o; o >>= 1) mx = fmaxf(mx, __shfl_xor(mx, o, 16));
    float e = __expf(logit - mx);
    float sum = e;
    #pragma unroll
    for (int o = 8; o; o >>= 1) sum += __shfl_xor(sum, o, 16);
    const float wgt = e / sum;

    const unsigned short* vb = V + ((size_t)b * NV) * 256 + h * 32 + 2 * s;
    float ax0 = 0.f, ay0 = 0.f, ax1 = 0.f, ay1 = 0.f;

    #pragma unroll
    for (int sp = 0; sp < 16; ++sp) {
        float ws  = __shfl(wgt, sp, 16);
        float lxs = __shfl(lx,  sp, 16);
        float lys = __shfl(ly,  sp, 16);
        int  ixs  = __shfl(ix,  sp, 16);
        int  iys  = __shfl(iy,  sp, 16);
        int  Ws   = __shfl(W,   sp, 16);
        int  Hs   = __shfl(H,   sp, 16);
        int  sts  = __shfl(st,  sp, 16);
        #pragma unroll
        for (int corner = 0; corner < 4; ++corner) {
            int dx = corner & 1, dy = corner >> 1;
            int xi = ixs + dx, yi = iys + dy;
            float valid = (xi >= 0 && xi < Ws && yi >= 0 && yi < Hs) ? 1.f : 0.f;
            int xc = min(max(xi, 0), Ws - 1);
            int yc = min(max(yi, 0), Hs - 1);
            float cw = ws * (dx ? lxs : 1.f - lxs) * (dy ? lys : 1.f - lys) * valid;
            const unsigned short* p = vb + (size_t)(sts + yc * Ws + xc) * 256;
            unsigned pv = *(const unsigned*)p;       // 2 bf16, unconditional
            if (corner & 1) {
                ax1 = fmaf(cw, bf2f((unsigned short)(pv & 0xFFFF)), ax1);
                ay1 = fmaf(cw, bf2f((unsigned short)(pv >> 16)), ay1);
            } else {
                ax0 = fmaf(cw, bf2f((unsigned short)(pv & 0xFFFF)), ax0);
                ay0 = fmaf(cw, bf2f((unsigned short)(pv >> 16)), ay0);
            }
        }
    }
    float2* o = (float2*)(OutS + (size_t)bq * 256 + h * 32);
    o[s] = make_float2(ax0 + ax1, ay0 + ay1);
}

// ---------------------------------------------------------------------------
extern "C" void kernel_launch(void* const* d_in, const int* in_sizes, int n_in,
                              void* d_out, int out_size, void* d_ws, size_t ws_size,
                              hipStream_t stream)
{
    const float* query  = (const float*)d_in[0];
    const float* value  = (const float*)d_in[1];
    const float* rp     = (const float*)d_in[2];
    // d_in[3] spatial_shapes: static, hardcoded
    const float* W_off  = (const float*)d_in[4];
    const float* b_off  = (const float*)d_in[5];
    const float* W_attn = (const float*)d_in[6];
    const float* b_attn = (const float*)d_in[7];
    const float* W_v    = (const float*)d_in[8];
    const float* b_v    = (const float*)d_in[9];
    const float* W_out  = (const float*)d_in[10];
    const float* b_out  = (const float*)d_in[11];

    char* ws = (char*)d_ws;
    size_t off = 0;
    unsigned short* Vbf = (unsigned short*)(ws + off); off += (size_t)MV * 256 * 2;
    float* qout         = (float*)(ws + off);          off += (size_t)MQ * NQOUT * 4;
    float* outs         = (float*)(ws + off);          off += (size_t)MQ * 256 * 4;
    unsigned short* WtV = (unsigned short*)(ws + off); off += 256 * 256 * 2;
    unsigned short* WtQ = (unsigned short*)(ws + off); off += 384 * 256 * 2;
    unsigned short* WtO = (unsigned short*)(ws + off); off += 256 * 256 * 2;
    float* biasQ        = (float*)(ws + off);          off += 384 * 4;

    prep_kernel<<<384, 256, 0, stream>>>(W_v, W_off, W_attn, W_out, b_off, b_attn,
                                         WtV, WtQ, WtO, biasQ);

    // v = value @ W_v + b_v -> bf16.  512 blocks (2/CU), 26 strips/block.
    gemm_ldsw<2, true, false><<<dim3(256, 2), 256, 0, stream>>>(
        value, WtV, b_v, nullptr, Vbf, MV, 256);

    // [off | attn-logits] = query @ [W_off | W_attn] + bias.  675 blocks.
    gemm_ldsw<2, false, false><<<dim3(225, 3), 256, 0, stream>>>(
        query, WtQ, biasQ, nullptr, qout, MQ, NQOUT);

    sample_kernel<<<(BS * NQ * HEADS) / 16, 256, 0, stream>>>(Vbf, qout, rp, outs);

    // out = out_s @ W_out + b_out + query.  450 blocks.
    gemm_ldsw<2, false, true><<<dim3(225, 2), 256, 0, stream>>>(
        outs, WtO, b_out, query, (float*)d_out, MQ, 256);
}

// Round 8
// 275.166 us; speedup vs baseline: 1.1543x; 1.0368x over previous
//
#include <hip/hip_runtime.h>
#include <hip/hip_bf16.h>

// Problem constants (fixed by reference file)
#define EMBED    256
#define HEADS    8
#define LEVELS   4
#define POINTS   4
#define HEAD_DIM 32
#define BS       8
#define NQ       900
#define NV       13294          // 100*100 + 50*50 + 25*25 + 13*13
#define MV       (BS*NV)        // 106352 = 6647*16
#define MQ       (BS*NQ)        // 7200   = 450*16
#define NQOUT    384            // 256 offset cols + 128 attn cols

typedef float  f32x4  __attribute__((ext_vector_type(4)));
typedef __bf16 bf16x8 __attribute__((ext_vector_type(8)));
typedef unsigned short ushort8  __attribute__((ext_vector_type(8)));
typedef unsigned short ushort4v __attribute__((ext_vector_type(4)));

__device__ __forceinline__ unsigned short f2bf(float f) {
    unsigned u = __builtin_bit_cast(unsigned, f);
    u += 0x7FFFu + ((u >> 16) & 1u);          // RNE
    return (unsigned short)(u >> 16);
}
__device__ __forceinline__ float bf2f(unsigned short h) {
    unsigned u = ((unsigned)h) << 16;
    return __builtin_bit_cast(float, u);
}

// ---------------------------------------------------------------------------
// Prep: transpose + cast weights to bf16 (B^T layout: [n][k], k contiguous)
// ---------------------------------------------------------------------------
__global__ __launch_bounds__(256) void prep_kernel(
    const float* __restrict__ Wv,  const float* __restrict__ Woff,
    const float* __restrict__ Wattn, const float* __restrict__ Wout,
    const float* __restrict__ boff, const float* __restrict__ battn,
    unsigned short* __restrict__ WtV, unsigned short* __restrict__ WtQ,
    unsigned short* __restrict__ WtO, float* __restrict__ biasQ)
{
    int n = blockIdx.x;      // 0..383
    int k = threadIdx.x;     // 0..255
    if (n < 256) {
        WtV[n * 256 + k] = f2bf(Wv [k * 256 + n]);
        WtO[n * 256 + k] = f2bf(Wout[k * 256 + n]);
        WtQ[n * 256 + k] = f2bf(Woff[k * 256 + n]);
    } else {
        int j = n - 256;
        WtQ[n * 256 + k] = f2bf(Wattn[k * 128 + j]);
    }
    if (k == 0) biasQ[n] = (n < 256) ? boff[n] : battn[n - 256];
}

// ---------------------------------------------------------------------------
// LDS-weight streaming GEMM (K=256), round-8: MORE WAVES. Round-7 structure
// was clean (VGPR=124, 0 conflicts) but only 6 waves/CU -> 2.6 KB
// outstanding/CU -> 1.76 TB/s (latency-BW arithmetic). Now 512-thr blocks:
// 8 waves = COLSETS(2) x PAR(4) strip-parities; LDS 128x264 ushorts = 67.6 KB
// -> 2 blocks/CU -> 16 waves/CU, ~2.7x outstanding traffic.
// Per wave: half-strip (K=128) register double-buffer (2x32 VGPRs), weights
// via ds_read_b128 (stride 264 ush = 132 dw = 4 mod 32 -> near-min aliasing).
// One barrier total (after weight staging).
//   C[M x Ntot] slice = A[M x 256](fp32) @ Bt[n][k]^T + bias (+ Ident)
// MFMA operands swapped (weights = A-op): lane's 4 acc regs = 4 consecutive
// output cols.
// ---------------------------------------------------------------------------
#define WLDK 264

template <int COLSETS, int PAR, bool OUT_BF16, bool ADD_ID>
__global__ __launch_bounds__(COLSETS * PAR * 64)
void gemm_ldsw(const float* __restrict__ A,
               const unsigned short* __restrict__ Bt,   // [Ntot][256] bf16
               const float* __restrict__ bias,          // [Ntot]
               const float* __restrict__ Ident,         // [M][Ntot] or null
               void* __restrict__ Cv, int M, int Ntot)
{
    constexpr int NC   = COLSETS * 64;     // cols per block
    constexpr int NTHR = COLSETS * PAR * 64;
    const int n0g = blockIdx.y * NC;
    __shared__ unsigned short Ws[NC * WLDK];

    const int tid = threadIdx.x;
    #pragma unroll
    for (int i = 0; i < (NC * 32) / NTHR; ++i) {        // vec8 tiles
        int flat = i * NTHR + tid;                      // ushort8 index
        int row = flat >> 5, col = (flat & 31) * 8;     // 32 vec8 per row
        *(ushort8*)&Ws[row * WLDK + col] =
            *(const ushort8*)(Bt + (size_t)(n0g + row) * 256 + col);
    }
    __syncthreads();                                    // the only barrier

    const int wave = tid >> 6, lane = tid & 63;
    const int colset = wave % COLSETS, parity = wave / COLSETS;
    const int lrow = lane & 15, kq = lane >> 4;
    const int n0 = colset * 64;

    f32x4 bj[4];
    #pragma unroll
    for (int j = 0; j < 4; ++j)
        bj[j] = *(const f32x4*)(bias + n0g + n0 + j * 16 + kq * 4);

    const int NS    = M / 16;
    const int chunk = (NS + gridDim.x - 1) / gridDim.x;
    const int send  = min(NS, blockIdx.x * chunk + chunk);
    int s = blockIdx.x * chunk + parity;
    if (s >= send) return;

    auto loadHalf = [&](f32x4 (&b)[8], int ss, int h) {
        const float* ab = A + (size_t)(ss * 16 + lrow) * 256 + h * 128 + kq * 8;
        #pragma unroll
        for (int c = 0; c < 4; ++c) {
            b[2 * c]     = *(const f32x4*)(ab + c * 32);
            b[2 * c + 1] = *(const f32x4*)(ab + c * 32 + 4);
        }
    };
    auto computeHalf = [&](f32x4 (&b)[8], int h, f32x4 (&acc)[4]) {
        #pragma unroll
        for (int c = 0; c < 4; ++c) {
            ushort8 vb;
            #pragma unroll
            for (int e = 0; e < 4; ++e) {
                vb[e]     = f2bf(b[2 * c][e]);
                vb[4 + e] = f2bf(b[2 * c + 1][e]);
            }
            bf16x8 vf = __builtin_bit_cast(bf16x8, vb);
            #pragma unroll
            for (int j = 0; j < 4; ++j) {
                bf16x8 wf = *(const bf16x8*)
                    &Ws[(n0 + j * 16 + lrow) * WLDK + h * 128 + c * 32 + kq * 8];
                acc[j] = __builtin_amdgcn_mfma_f32_16x16x32_bf16(wf, vf, acc[j], 0, 0, 0);
            }
        }
    };

    f32x4 b0[8], b1[8];
    loadHalf(b0, s, 0);
    while (true) {
        loadHalf(b1, s, 1);
        f32x4 acc[4];
        #pragma unroll
        for (int j = 0; j < 4; ++j) acc[j] = (f32x4)0.f;
        computeHalf(b0, 0, acc);            // waits only on b0
        const int sn = s + PAR;
        const bool more = sn < send;
        if (more) loadHalf(b0, sn, 0);      // in flight during computeHalf(b1)
        computeHalf(b1, 1, acc);

        const size_t crow = (size_t)(s * 16 + lrow) * Ntot + n0g + n0 + kq * 4;
        #pragma unroll
        for (int j = 0; j < 4; ++j) {
            f32x4 r = acc[j] + bj[j];
            if (ADD_ID)
                r += *(const f32x4*)(Ident + crow + j * 16);
            if (OUT_BF16) {
                ushort4v o;
                #pragma unroll
                for (int e = 0; e < 4; ++e) o[e] = f2bf(r[e]);
                *(ushort4v*)((unsigned short*)Cv + crow + j * 16) = o;
            } else {
                *(f32x4*)((float*)Cv + crow + j * 16) = r;
            }
        }
        if (!more) break;
        s = sn;
    }
}

// ---------------------------------------------------------------------------
// Sampling v2: 16 lanes per (b,q,h); lane s owns sample s. ALL corner math
// (validity, clamp, flat index, corner weights) hoisted to per-lane
// precompute; the 16-iteration broadcast loop is only 8 shuffles + 4 loads
// + 8 fma -> minimal VALU between loads, loads free to pipeline.
// ---------------------------------------------------------------------------
__device__ const int   LVL_W[4]  = {100, 50, 25, 13};
__device__ const int   LVL_H[4]  = {100, 50, 25, 13};
__device__ const int   LVL_S[4]  = {0, 10000, 12500, 13125};

__global__ __launch_bounds__(256) void sample_kernel(
    const unsigned short* __restrict__ V,   // (BS*NV, 256) bf16
    const float* __restrict__ Qout,         // (BS*NQ, 384)
    const float* __restrict__ RP,           // (BS, NQ, 4, 2)
    float* __restrict__ OutS)               // (BS*NQ, 256)
{
    const int gid = blockIdx.x * 16 + (threadIdx.x >> 4);   // triple index
    const int s   = threadIdx.x & 15;                       // lane-in-group
    const int h   = gid & 7;
    const int bq  = gid >> 3;                               // b*NQ + q
    const int b   = bq / NQ;

    const float* qrow = Qout + (size_t)bq * NQOUT;

    const int l = s >> 2;
    const float ox = qrow[h * 32 + 2 * s];
    const float oy = qrow[h * 32 + 2 * s + 1];
    float logit    = qrow[256 + h * 16 + s];
    const float rpx = RP[((size_t)bq * 4 + l) * 2 + 0];
    const float rpy = RP[((size_t)bq * 4 + l) * 2 + 1];
    const int W = LVL_W[l], H = LVL_H[l], st = LVL_S[l];
    float x = rpx * (float)W + ox - 0.5f;
    float y = rpy * (float)H + oy - 0.5f;
    float fx = floorf(x), fy = floorf(y);
    float lx = x - fx, ly = y - fy;
    int x0 = (int)fx, y0 = (int)fy;
    int x1 = x0 + 1,  y1 = y0 + 1;

    // softmax over the 16 lanes of this group
    float mx = logit;
    #pragma unroll
    for (int o = 8; o; o >>= 1) mx = fmaxf(mx, __shfl_xor(mx, o, 16));
    float e = __expf(logit - mx);
    float sum = e;
    #pragma unroll
    for (int o = 8; o; o >>= 1) sum += __shfl_xor(sum, o, 16);
    const float wgt = e / sum;

    // per-lane corner precompute (hoisted out of the broadcast loop)
    const float vx0 = (x0 >= 0 && x0 < W) ? 1.f : 0.f;
    const float vx1 = (x1 >= 0 && x1 < W) ? 1.f : 0.f;
    const float vy0 = (y0 >= 0 && y0 < H) ? 1.f : 0.f;
    const float vy1 = (y1 >= 0 && y1 < H) ? 1.f : 0.f;
    const int cx0 = min(max(x0, 0), W - 1), cx1 = min(max(x1, 0), W - 1);
    const int cy0 = min(max(y0, 0), H - 1), cy1 = min(max(y1, 0), H - 1);
    float w00 = wgt * (1.f - lx) * (1.f - ly) * vx0 * vy0;
    float w10 = wgt * lx * (1.f - ly) * vx1 * vy0;
    float w01 = wgt * (1.f - lx) * ly * vx0 * vy1;
    float w11 = wgt * lx * ly * vx1 * vy1;
    int i00 = st + cy0 * W + cx0;
    int i10 = st + cy0 * W + cx1;
    int i01 = st + cy1 * W + cx0;
    int i11 = st + cy1 * W + cx1;

    const unsigned short* vb = V + ((size_t)b * NV) * 256 + h * 32 + 2 * s;
    float ax0 = 0.f, ay0 = 0.f, ax1 = 0.f, ay1 = 0.f;

    #pragma unroll
    for (int sp = 0; sp < 16; ++sp) {
        int   j00 = __shfl(i00, sp, 16), j10 = __shfl(i10, sp, 16);
        int   j01 = __shfl(i01, sp, 16), j11 = __shfl(i11, sp, 16);
        float u00 = __shfl(w00, sp, 16), u10 = __shfl(w10, sp, 16);
        float u01 = __shfl(w01, sp, 16), u11 = __shfl(w11, sp, 16);
        unsigned p00 = *(const unsigned*)(vb + (size_t)j00 * 256);
        unsigned p10 = *(const unsigned*)(vb + (size_t)j10 * 256);
        unsigned p01 = *(const unsigned*)(vb + (size_t)j01 * 256);
        unsigned p11 = *(const unsigned*)(vb + (size_t)j11 * 256);
        ax0 = fmaf(u00, bf2f((unsigned short)(p00 & 0xFFFF)), ax0);
        ay0 = fmaf(u00, bf2f((unsigned short)(p00 >> 16)), ay0);
        ax1 = fmaf(u10, bf2f((unsigned short)(p10 & 0xFFFF)), ax1);
        ay1 = fmaf(u10, bf2f((unsigned short)(p10 >> 16)), ay1);
        ax0 = fmaf(u01, bf2f((unsigned short)(p01 & 0xFFFF)), ax0);
        ay0 = fmaf(u01, bf2f((unsigned short)(p01 >> 16)), ay0);
        ax1 = fmaf(u11, bf2f((unsigned short)(p11 & 0xFFFF)), ax1);
        ay1 = fmaf(u11, bf2f((unsigned short)(p11 >> 16)), ay1);
    }
    float2* o = (float2*)(OutS + (size_t)bq * 256 + h * 32);
    o[s] = make_float2(ax0 + ax1, ay0 + ay1);
}

// ---------------------------------------------------------------------------
extern "C" void kernel_launch(void* const* d_in, const int* in_sizes, int n_in,
                              void* d_out, int out_size, void* d_ws, size_t ws_size,
                              hipStream_t stream)
{
    const float* query  = (const float*)d_in[0];
    const float* value  = (const float*)d_in[1];
    const float* rp     = (const float*)d_in[2];
    // d_in[3] spatial_shapes: static, hardcoded
    const float* W_off  = (const float*)d_in[4];
    const float* b_off  = (const float*)d_in[5];
    const float* W_attn = (const float*)d_in[6];
    const float* b_attn = (const float*)d_in[7];
    const float* W_v    = (const float*)d_in[8];
    const float* b_v    = (const float*)d_in[9];
    const float* W_out  = (const float*)d_in[10];
    const float* b_out  = (const float*)d_in[11];

    char* ws = (char*)d_ws;
    size_t off = 0;
    unsigned short* Vbf = (unsigned short*)(ws + off); off += (size_t)MV * 256 * 2;
    float* qout         = (float*)(ws + off);          off += (size_t)MQ * NQOUT * 4;
    float* outs         = (float*)(ws + off);          off += (size_t)MQ * 256 * 4;
    unsigned short* WtV = (unsigned short*)(ws + off); off += 256 * 256 * 2;
    unsigned short* WtQ = (unsigned short*)(ws + off); off += 384 * 256 * 2;
    unsigned short* WtO = (unsigned short*)(ws + off); off += 256 * 256 * 2;
    float* biasQ        = (float*)(ws + off);          off += 384 * 4;

    prep_kernel<<<384, 256, 0, stream>>>(W_v, W_off, W_attn, W_out, b_off, b_attn,
                                         WtV, WtQ, WtO, biasQ);

    // v = value @ W_v + b_v -> bf16.  512 blocks (2/CU), 16 waves/CU.
    gemm_ldsw<2, 4, true, false><<<dim3(256, 2), 512, 0, stream>>>(
        value, WtV, b_v, nullptr, Vbf, MV, 256);

    // [off | attn-logits] = query @ [W_off | W_attn] + bias.  171 blocks.
    gemm_ldsw<2, 4, false, false><<<dim3(57, 3), 512, 0, stream>>>(
        query, WtQ, biasQ, nullptr, qout, MQ, NQOUT);

    sample_kernel<<<(BS * NQ * HEADS) / 16, 256, 0, stream>>>(Vbf, qout, rp, outs);

    // out = out_s @ W_out + b_out + query.  114 blocks.
    gemm_ldsw<2, 4, false, true><<<dim3(57, 2), 512, 0, stream>>>(
        outs, WtO, b_out, query, (float*)d_out, MQ, 256);
}